// Round 13
// baseline (168.441 us; speedup 1.0000x reference)
//
#include <hip/hip_runtime.h>

#define N_NODES 10000
#define E_EDGES 640000
#define C 128
#define NB 256
#define TPB 512
#define EPB (E_EDGES / NB)      // 2500 edges per block
#define QPB (EPB / 4)           // 625 quads per block
#define CCH 40                  // nodes per block in P2 (256*40 = 10240)

// Spin barrier: release-add arrival; ACQUIRE poll every iteration (always
// fresh — R8 lesson: relaxed polls can be served stale forever; idempotent
// RMW spins get folded to relaxed loads by LLVM). s_sleep(32) ~0.85us pacing
// keeps the invalidate rate ~300x below R5's storm.
__device__ __forceinline__ void bar_spin(unsigned* c, unsigned tgt) {
    __syncthreads();
    if (threadIdx.x == 0) {
        __hip_atomic_fetch_add(c, 1u, __ATOMIC_RELEASE, __HIP_MEMORY_SCOPE_AGENT);
        while (__hip_atomic_load(c, __ATOMIC_ACQUIRE, __HIP_MEMORY_SCOPE_AGENT) < tgt)
            __builtin_amdgcn_s_sleep(32);
    }
    __syncthreads();
}

__global__ __launch_bounds__(TPB) void k_fused(
    const int* __restrict__ row, const int* __restrict__ col,
    const float* __restrict__ w,
    const float* __restrict__ W1, const float* __restrict__ b1,
    const float* __restrict__ W2, const float* __restrict__ b2,
    float* __restrict__ deg, float* __restrict__ ta, float* __restrict__ tb,
    float* __restrict__ s1, float* __restrict__ g,
    unsigned* __restrict__ ctrl, float* __restrict__ out)
{
    __shared__ float sal[CCH], sbe[CCH], sp[TPB];
    __shared__ int lastFlag;
    const int tid = threadIdx.x, bid = blockIdx.x;
    const int e0 = bid * EPB;
    const int4*   row4 = (const int4*)(row + e0);
    const int4*   col4 = (const int4*)(col + e0);
    const float4* w4   = (const float4*)(w + e0);

    // ---------- P0: deg via native global atomics; block 0 lanes<128 do s1 ----------
    if (bid == 0 && tid < C) {
        float s = 0.0f;
        #pragma unroll 16
        for (int k = 0; k < C; ++k) s += W1[k * C + tid];   // coalesced across tid
        s1[tid] = s;
    } else {
        const int t0     = (bid == 0) ? tid - C : tid;
        const int stride = (bid == 0) ? TPB - C : TPB;
        for (int k = t0; k < QPB; k += stride) {
            int4 cc = col4[k]; float4 ww = w4[k];
            unsafeAtomicAdd(&deg[cc.x], ww.x);              // fire-and-forget fadd
            unsafeAtomicAdd(&deg[cc.y], ww.y);
            unsafeAtomicAdd(&deg[cc.z], ww.z);
            unsafeAtomicAdd(&deg[cc.w], ww.w);
        }
    }
    bar_spin(ctrl + 0, NB);

    // ---------- P1: scatter with on-the-fly dinv = rsqrt(1+deg) ----------
    for (int k = tid; k < QPB; k += TPB) {
        int4 rr = row4[k]; int4 cc = col4[k]; float4 ww = w4[k];
        float dr0 = rsqrtf(1.0f + deg[rr.x]), dc0 = rsqrtf(1.0f + deg[cc.x]);
        float dr1 = rsqrtf(1.0f + deg[rr.y]), dc1 = rsqrtf(1.0f + deg[cc.y]);
        float dr2 = rsqrtf(1.0f + deg[rr.z]), dc2 = rsqrtf(1.0f + deg[cc.z]);
        float dr3 = rsqrtf(1.0f + deg[rr.w]), dc3 = rsqrtf(1.0f + deg[cc.w]);
        unsafeAtomicAdd(&ta[cc.x], ww.x * dr0);
        unsafeAtomicAdd(&tb[rr.x], ww.x * dc0);
        unsafeAtomicAdd(&ta[cc.y], ww.y * dr1);
        unsafeAtomicAdd(&tb[rr.y], ww.y * dc1);
        unsafeAtomicAdd(&ta[cc.z], ww.z * dr2);
        unsafeAtomicAdd(&tb[rr.z], ww.z * dc2);
        unsafeAtomicAdd(&ta[cc.w], ww.w * dr3);
        unsafeAtomicAdd(&tb[rr.w], ww.w * dc3);
    }
    bar_spin(ctrl + 32, NB);

    // ---------- P2: alpha/beta for CCH nodes, channel reduce, g atomics ----------
    const int i0 = bid * CCH;
    int n = N_NODES - i0;
    n = n < 0 ? 0 : (n > CCH ? CCH : n);
    if (tid < n) {                                          // alpha
        int i = i0 + tid;
        float di = rsqrtf(1.0f + deg[i]);
        sal[tid] = fmaf(di, ta[i], di * di);
    } else if (tid >= 256 && tid - 256 < n) {               // beta (parallel waves)
        int t = tid - 256;
        int i = i0 + t;
        float di = rsqrtf(1.0f + deg[i]);
        sbe[t] = fmaf(di, tb[i], di * di);
    }
    __syncthreads();
    const int j   = tid & (C - 1);
    const int sub = tid >> 7;                               // 4 channel-subsets
    float s1j = s1[j], b1j = b1[j], acc = 0.0f;
    for (int t = sub; t < n; t += 4) {                      // LDS broadcast reads
        float h = fmaf(sal[t], s1j, b1j);
        acc += sbe[t] * fmaxf(h, 0.0f);                     // exact relu
    }
    sp[tid] = acc;
    __syncthreads();
    if (tid < C) {
        float G = sp[tid] + sp[tid + 128] + sp[tid + 256] + sp[tid + 384];
        unsafeAtomicAdd(&g[tid], G);
    }

    // ---------- P3: non-blocking last-block gate -> final matvec ----------
    __syncthreads();                                        // g atomics drained
    if (tid == 0) {
        unsigned old = __hip_atomic_fetch_add(ctrl + 64, 1u, __ATOMIC_ACQ_REL,
                                              __HIP_MEMORY_SCOPE_AGENT);
        lastFlag = (old == NB - 1);
        if (lastFlag) __builtin_amdgcn_fence(__ATOMIC_ACQUIRE, "agent");
    }
    __syncthreads();
    if (lastFlag) {
        float a2 = 0.0f;
        #pragma unroll
        for (int k = sub * 32; k < sub * 32 + 32; ++k)
            a2 += g[k] * W2[k * C + j];                     // g broadcast, W2 coalesced
        sp[tid] = a2;
        __syncthreads();
        if (tid < C) {
            float r = sp[tid] + sp[tid + 128] + sp[tid + 256] + sp[tid + 384];
            out[tid] = r * (1.0f / (float)N_NODES) + b2[tid];
        }
    }
}

extern "C" void kernel_launch(void* const* d_in, const int* in_sizes, int n_in,
                              void* d_out, int out_size, void* d_ws, size_t ws_size,
                              hipStream_t stream) {
    const int*   eidx = (const int*)d_in[1];
    const int*   row  = eidx;             // edge_index[0]
    const int*   col  = eidx + E_EDGES;   // edge_index[1]
    const float* w    = (const float*)d_in[2];
    const float* W1   = (const float*)d_in[3];
    const float* b1   = (const float*)d_in[4];
    const float* W2   = (const float*)d_in[5];
    const float* b2   = (const float*)d_in[6];
    float* out = (float*)d_out;
    float* ws  = (float*)d_ws;

    float*    deg  = ws;                                  // N
    float*    ta   = deg + N_NODES;                       // N
    float*    tb   = ta + N_NODES;                        // N
    float*    g    = tb + N_NODES;                        // C
    unsigned* ctrl = (unsigned*)(g + C);                  // 96 uints (3 counters)
    float*    s1   = (float*)(ctrl + 96);                 // C (not in memset)

    // zero deg/ta/tb/g/ctrl in one small memset (~118 KB)
    size_t zbytes = (3 * N_NODES + C) * sizeof(float) + 96 * sizeof(unsigned);
    (void)hipMemsetAsync(ws, 0, zbytes, stream);
    k_fused<<<NB, TPB, 0, stream>>>(row, col, w, W1, b1, W2, b2,
                                    deg, ta, tb, s1, g, ctrl, out);
}

// Round 14
// 53.120 us; speedup vs baseline: 3.1709x; 3.1709x over previous
//
#include <hip/hip_runtime.h>

#define N_NODES 10000
#define E_EDGES 640000
#define C 128
#define NBA 128           // deg-partial blocks
#define NBS 128           // ta (and tb) partial count; scatter kernel = 2*NBS blocks
#define NBC 125           // greduce blocks (125*80 = 10000 exactly)
#define CCH 80            // nodes per greduce block
#define FPB 40            // dinv nodes folded per scatter block (256*40 = 10240)

typedef float vf4 __attribute__((ext_vector_type(4)));

// Native LDS fp32 add: relaxed, workgroup scope -> ds_add_f32 (no CAS loop).
__device__ __forceinline__ void lds_add(float* p, float v) {
    __hip_atomic_fetch_add(p, v, __ATOMIC_RELAXED, __HIP_MEMORY_SCOPE_WORKGROUP);
}

// Acquire-poll spin barrier. Acquire EVERY poll (fresh by construction — R8
// lesson: relaxed/idempotent-RMW polls can be stale forever). s_sleep(32)
// (~0.85us) pacing keeps the invalidate traffic negligible (vs R5's storm).
__device__ __forceinline__ void bar_spin(unsigned* c, unsigned tgt) {
    __syncthreads();
    if (threadIdx.x == 0) {
        __hip_atomic_fetch_add(c, 1u, __ATOMIC_RELEASE, __HIP_MEMORY_SCOPE_AGENT);
        while (__hip_atomic_load(c, __ATOMIC_ACQUIRE, __HIP_MEMORY_SCOPE_AGENT) < tgt)
            __builtin_amdgcn_s_sleep(32);
    }
    __syncthreads();
}

// ---------------- k1: deg partials; aux block: s1 + zero g/ctrl ----------------
__global__ __launch_bounds__(512) void k_deg(const int* __restrict__ col,
                                             const float* __restrict__ w,
                                             const float* __restrict__ W1,
                                             float* __restrict__ degp,
                                             float* __restrict__ s1,
                                             float* __restrict__ g,
                                             unsigned* __restrict__ ctrl) {
    const int tid = threadIdx.x, bid = blockIdx.x;
    if (bid == NBA) {                                     // aux block
        if (tid < C) {
            float s = 0.0f;
            #pragma unroll 16
            for (int k = 0; k < C; ++k) s += W1[k * C + tid];  // coalesced
            s1[tid] = s;
            g[tid]  = 0.0f;
        }
        if (tid < 2) ctrl[tid * 32] = 0u;                 // spin + gate counters
        return;
    }
    __shared__ float sdeg[N_NODES];                       // 40 KB, 4 blk/CU
    vf4 z = {0.f, 0.f, 0.f, 0.f};
    for (int i = tid; i < N_NODES / 4; i += 512) ((vf4*)sdeg)[i] = z;
    __syncthreads();
    const int epb = E_EDGES / NBA;                        // 5000
    const int4*   col4 = (const int4*)(col + bid * epb);
    const float4* w4   = (const float4*)(w + bid * epb);
    for (int k = tid; k < epb / 4; k += 512) {
        int4 cc = col4[k]; float4 ww = w4[k];
        lds_add(&sdeg[cc.x], ww.x);
        lds_add(&sdeg[cc.y], ww.y);
        lds_add(&sdeg[cc.z], ww.z);
        lds_add(&sdeg[cc.w], ww.w);
    }
    __syncthreads();
    float* dst = degp + (size_t)bid * N_NODES;
    for (int i = tid; i < N_NODES / 4; i += 512)
        ((vf4*)dst)[i] = ((const vf4*)sdeg)[i];           // plain coalesced flush
}

// -------- k2: cooperative dinv fold (40 nodes/block) + spin barrier + scatter ------
__global__ __launch_bounds__(512) void k_scatter(const int* __restrict__ row,
                                                 const int* __restrict__ col,
                                                 const float* __restrict__ w,
                                                 const float* __restrict__ degp,
                                                 float* __restrict__ dinv,
                                                 float* __restrict__ tap,
                                                 float* __restrict__ tbp,
                                                 unsigned* __restrict__ ctrl) {
    __shared__ float st[N_NODES];                         // 40 KB, 4 blk/CU
    __shared__ float sf[8][FPB];                          // fold scratch
    const int tid = threadIdx.x;
    const bool isA = blockIdx.x < NBS;
    const int bid  = isA ? blockIdx.x : blockIdx.x - NBS;
    vf4 z = {0.f, 0.f, 0.f, 0.f};
    for (int i = tid; i < N_NODES / 4; i += 512) ((vf4*)st)[i] = z;

    // cooperative dinv fold: this block owns nodes [i0, i0+FPB)
    {
        const int i0 = blockIdx.x * FPB;
        const int node = tid & 63;                        // 0..63 (first FPB valid)
        const int grp  = tid >> 6;                        // 8 groups x 16 partials
        if (node < FPB && i0 + node < N_NODES) {
            float d = 0.0f;
            #pragma unroll 16
            for (int b = grp * 16; b < grp * 16 + 16; ++b)
                d += degp[(size_t)b * N_NODES + i0 + node];
            sf[grp][node] = d;
        }
        __syncthreads();
        if (tid < FPB && i0 + tid < N_NODES) {
            float d = 1.0f;                               // self-loop weight
            #pragma unroll
            for (int gp = 0; gp < 8; ++gp) d += sf[gp][tid];
            dinv[i0 + tid] = rsqrtf(d);
        }
    }
    bar_spin(ctrl, 2 * NBS);                              // all dinv published

    const int epb = E_EDGES / NBS;                        // 5000
    const int4*   row4 = (const int4*)(row + bid * epb);
    const int4*   col4 = (const int4*)(col + bid * epb);
    const float4* w4   = (const float4*)(w + bid * epb);
    if (isA) {                                            // t_a[c] += w * dinv[r]
        for (int k = tid; k < epb / 4; k += 512) {
            int4 rr = row4[k]; int4 cc = col4[k]; float4 ww = w4[k];
            lds_add(&st[cc.x], ww.x * dinv[rr.x]);
            lds_add(&st[cc.y], ww.y * dinv[rr.y]);
            lds_add(&st[cc.z], ww.z * dinv[rr.z]);
            lds_add(&st[cc.w], ww.w * dinv[rr.w]);
        }
    } else {                                              // t_b[r] += w * dinv[c]
        for (int k = tid; k < epb / 4; k += 512) {
            int4 rr = row4[k]; int4 cc = col4[k]; float4 ww = w4[k];
            lds_add(&st[rr.x], ww.x * dinv[cc.x]);
            lds_add(&st[rr.y], ww.y * dinv[cc.y]);
            lds_add(&st[rr.z], ww.z * dinv[cc.z]);
            lds_add(&st[rr.w], ww.w * dinv[cc.w]);
        }
    }
    __syncthreads();
    float* dst = (isA ? tap : tbp) + (size_t)bid * N_NODES;
    for (int i = tid; i < N_NODES / 4; i += 512)
        ((vf4*)dst)[i] = ((const vf4*)st)[i];             // coalesced flush
}

// ---------------- k3: fold -> alpha/beta, channel reduce, g atomics, gated final ----
__global__ __launch_bounds__(512) void k_greduce(const float* __restrict__ tap,
                                                 const float* __restrict__ tbp,
                                                 const float* __restrict__ dinv,
                                                 const float* __restrict__ s1,
                                                 const float* __restrict__ b1,
                                                 const float* __restrict__ W2,
                                                 const float* __restrict__ b2,
                                                 float* __restrict__ g,
                                                 unsigned* __restrict__ ctrl,
                                                 float* __restrict__ out) {
    __shared__ float sal[CCH], sbe[CCH], sp[512];
    __shared__ int lastFlag;
    const int tid = threadIdx.x, bid = blockIdx.x;
    const int i0 = bid * CCH;
    int n = N_NODES - i0;
    n = n < 0 ? 0 : (n > CCH ? CCH : n);
    if (tid < n) {                                        // fold t_a -> alpha
        int i = i0 + tid;
        float ta = 0.0f;
        #pragma unroll 16
        for (int b = 0; b < NBS; ++b) ta += tap[(size_t)b * N_NODES + i];
        float di = dinv[i];
        sal[tid] = fmaf(di, ta, di * di);
    } else if (tid >= 256 && tid - 256 < n) {             // fold t_b -> beta (parallel)
        int t = tid - 256;
        int i = i0 + t;
        float tb = 0.0f;
        #pragma unroll 16
        for (int b = 0; b < NBS; ++b) tb += tbp[(size_t)b * N_NODES + i];
        float di = dinv[i];
        sbe[t] = fmaf(di, tb, di * di);
    }
    __syncthreads();
    const int j   = tid & (C - 1);
    const int sub = tid >> 7;                             // 4 channel-subsets
    float s1j = s1[j], b1j = b1[j], acc = 0.0f;
    for (int t = sub; t < n; t += 4) {                    // LDS broadcast reads
        float h = fmaf(sal[t], s1j, b1j);
        acc += sbe[t] * fmaxf(h, 0.0f);                   // exact relu
    }
    sp[tid] = acc;
    __syncthreads();
    if (tid < C) {
        float G = sp[tid] + sp[tid + 128] + sp[tid + 256] + sp[tid + 384];
        unsafeAtomicAdd(&g[tid], G);                      // 16K atomics total: cheap
    }
    // ---- non-blocking last-block gate (validated R9-R12) ----
    __syncthreads();                                      // all g-atomics issued
    if (tid == 0) {
        unsigned old = __hip_atomic_fetch_add(ctrl + 32, 1u, __ATOMIC_ACQ_REL,
                                              __HIP_MEMORY_SCOPE_AGENT);
        lastFlag = (old == NBC - 1);
        if (lastFlag) __builtin_amdgcn_fence(__ATOMIC_ACQUIRE, "agent");
    }
    __syncthreads();
    if (lastFlag) {
        float a2 = 0.0f;
        #pragma unroll
        for (int k = sub * 32; k < sub * 32 + 32; ++k)
            a2 += g[k] * W2[k * C + j];                   // g broadcast, W2 coalesced
        sp[tid] = a2;
        __syncthreads();
        if (tid < C) {
            float r = sp[tid] + sp[tid + 128] + sp[tid + 256] + sp[tid + 384];
            out[tid] = r * (1.0f / (float)N_NODES) + b2[tid];
        }
    }
}

extern "C" void kernel_launch(void* const* d_in, const int* in_sizes, int n_in,
                              void* d_out, int out_size, void* d_ws, size_t ws_size,
                              hipStream_t stream) {
    const int*   eidx = (const int*)d_in[1];
    const int*   row  = eidx;             // edge_index[0]
    const int*   col  = eidx + E_EDGES;   // edge_index[1]
    const float* w    = (const float*)d_in[2];
    const float* W1   = (const float*)d_in[3];
    const float* b1   = (const float*)d_in[4];
    const float* W2   = (const float*)d_in[5];
    const float* b2   = (const float*)d_in[6];
    float* out = (float*)d_out;
    float* ws  = (float*)d_ws;

    float*    degp = ws;                                  // NBA * N
    float*    tap  = degp + (size_t)NBA * N_NODES;        // NBS * N
    float*    tbp  = tap  + (size_t)NBS * N_NODES;        // NBS * N
    float*    dinv = tbp  + (size_t)NBS * N_NODES;        // N
    float*    s1   = dinv + N_NODES;                      // C
    float*    g    = s1 + C;                              // C
    unsigned* ctrl = (unsigned*)(g + C);                  // 2 counters, 128B apart

    k_deg    <<<NBA + 1, 512, 0, stream>>>(col, w, W1, degp, s1, g, ctrl);
    k_scatter<<<2 * NBS, 512, 0, stream>>>(row, col, w, degp, dinv, tap, tbp, ctrl);
    k_greduce<<<NBC, 512, 0, stream>>>(tap, tbp, dinv, s1, b1, W2, b2, g, ctrl, out);
}